// Round 2
// baseline (954.292 us; speedup 1.0000x reference)
//
#include <hip/hip_runtime.h>

// Problem: per-node MLP 16->256->128->6->128->256->1 (tanh...sigmoid) on
// edge_attr.reshape(500000,16). x / edge_index are dead inputs.
//
// Scheme: transposed activations (feature-major), f16 MFMA 16x16x32,
// weights pre-fragmented into per-lane A-operand layout by prep kernel into a
// __device__ image; persistent blocks stage it to LDS once (global_load_lds
// width 16), then each wave pushes 32 nodes through all layers using only
// registers + ds_bpermute (__shfl) for the C->B layout transform.

#define N_NODES 500000

// ---- weight-image layout (bytes). All offsets 16B-aligned. ----
#define OFF_W1 0        // 16 blocks x 512B (L1: K=16 -> only lanes 0..31 hold data)
#define OFF_W2 8192     // 64 blocks x 1KB  (L2: 256->128, mi*8+ki)
#define OFF_W3 73728    // 4  blocks x 1KB  (L3: 128->16(6 valid), ki)
#define OFF_W4 77824    // 8  blocks x 1KB  (L4: 6(pad32)->128, mi)
#define OFF_W5 86016    // 64 blocks x 1KB  (L5: 128->256, mi*4+ki)
#define OFF_WO 151552   // 256 f32 (output weights)
#define OFF_B1 152576   // 256 f32
#define OFF_B2 153600   // 128 f32
#define OFF_B3 154112   // 16  f32 (6 valid, rest 0)
#define OFF_B4 154176   // 128 f32
#define OFF_B5 154688   // 256 f32
#define IMG_BYTES 155712
// chunks of 16B: 9732 = 19 rounds x 8 waves x 64 lanes + 4 tail chunks

typedef _Float16 half8  __attribute__((ext_vector_type(8)));
typedef __fp16   pk16x2 __attribute__((ext_vector_type(2)));   // cvt_pkrtz result type
typedef float    f32x4  __attribute__((ext_vector_type(4)));

__device__ __align__(16) char g_img[IMG_BYTES];

union H8 { half8 h; int i[4]; };

static __device__ __forceinline__ unsigned pack_f16_rne(float a, float b) {
  _Float16 ha = (_Float16)a, hb = (_Float16)b;
  unsigned short ua = __builtin_bit_cast(unsigned short, ha);
  unsigned short ub = __builtin_bit_cast(unsigned short, hb);
  return (unsigned)ua | ((unsigned)ub << 16);
}

static __device__ __forceinline__ int pkrtz(float a, float b) {
  pk16x2 h = __builtin_amdgcn_cvt_pkrtz(a, b);
  return __builtin_bit_cast(int, h);
}

static __device__ __forceinline__ float tanh_f(float x) {
  // tanh(x) = 1 - 2/(exp2(2x*log2e)+1); exact at +-inf, ~1e-6 abs err.
  float e = __builtin_amdgcn_exp2f(x * 2.8853900817779268f);
  float r = __builtin_amdgcn_rcpf(e + 1.0f);
  return __builtin_fmaf(-2.0f, r, 1.0f);
}

static __device__ __forceinline__ float sigmoid_f(float x) {
  float e = __builtin_amdgcn_exp2f(x * -1.4426950408889634f);
  return __builtin_amdgcn_rcpf(1.0f + e);
}

static __device__ __forceinline__ f32x4 MFMA(const H8& A, const int* b, f32x4 acc) {
  H8 B; B.i[0] = b[0]; B.i[1] = b[1]; B.i[2] = b[2]; B.i[3] = b[3];
  return __builtin_amdgcn_mfma_f32_16x16x32_f16(A.h, B.h, acc, 0, 0, 0);
}

// ---------------- prep: gather/transpose/convert weights into g_img ----------------
// A-fragment layout per 1KB block (mi,ki): lane L holds 16B = 8 f16 =
// W^T[16*mi + (L&15)][32*ki + 8*(L>>4) + 0..7]  (W^T[fout][fin] = W[fin][fout])
__global__ void gnn_prep(const float* __restrict__ W1,  const float* __restrict__ b1,
                         const float* __restrict__ We1, const float* __restrict__ be1,
                         const float* __restrict__ We2, const float* __restrict__ be2,
                         const float* __restrict__ Wd1, const float* __restrict__ bd1,
                         const float* __restrict__ Wd2, const float* __restrict__ bd2,
                         const float* __restrict__ Wo)
{
  int t = blockIdx.x * 256 + threadIdx.x;
  int off = t * 4;
  if (off >= IMG_BYTES) return;
  unsigned val;
  if (off < OFF_W2) {                     // L1: 512B half-blocks (K=16)
    int rel = off;
    int mi = rel >> 9, li = (rel >> 4) & 31, j2 = (rel >> 2) & 3;
    int fout = mi * 16 + (li & 15);
    int k0 = (li >> 4) * 8 + j2 * 2;      // 0..15
    val = pack_f16_rne(W1[k0 * 256 + fout], W1[(k0 + 1) * 256 + fout]);
  } else if (off < OFF_W3) {              // L2: 256->128
    int rel = off - OFF_W2;
    int blk = rel >> 10, li = (rel >> 4) & 63, j2 = (rel >> 2) & 3;
    int mi = blk >> 3, ki = blk & 7;
    int fout = mi * 16 + (li & 15);
    int k0 = ki * 32 + (li >> 4) * 8 + j2 * 2;
    val = pack_f16_rne(We1[k0 * 128 + fout], We1[(k0 + 1) * 128 + fout]);
  } else if (off < OFF_W4) {              // L3: 128->6 (fout padded to 16 with 0)
    int rel = off - OFF_W3;
    int ki = rel >> 10, li = (rel >> 4) & 63, j2 = (rel >> 2) & 3;
    int fo = li & 15;
    int k0 = ki * 32 + (li >> 4) * 8 + j2 * 2;
    float a = (fo < 6) ? We2[k0 * 6 + fo] : 0.0f;
    float b = (fo < 6) ? We2[(k0 + 1) * 6 + fo] : 0.0f;
    val = pack_f16_rne(a, b);
  } else if (off < OFF_W5) {              // L4: 6->128 (K padded to 32 with 0)
    int rel = off - OFF_W4;
    int mi = rel >> 10, li = (rel >> 4) & 63, j2 = (rel >> 2) & 3;
    int fout = mi * 16 + (li & 15);
    int k0 = (li >> 4) * 8 + j2 * 2;
    float a = (k0 < 6)     ? Wd1[k0 * 128 + fout]       : 0.0f;
    float b = (k0 + 1 < 6) ? Wd1[(k0 + 1) * 128 + fout] : 0.0f;
    val = pack_f16_rne(a, b);
  } else if (off < OFF_WO) {              // L5: 128->256
    int rel = off - OFF_W5;
    int blk = rel >> 10, li = (rel >> 4) & 63, j2 = (rel >> 2) & 3;
    int mi = blk >> 2, ki = blk & 3;
    int fout = mi * 16 + (li & 15);
    int k0 = ki * 32 + (li >> 4) * 8 + j2 * 2;
    val = pack_f16_rne(Wd2[k0 * 256 + fout], Wd2[(k0 + 1) * 256 + fout]);
  } else if (off < OFF_B1) {
    val = __builtin_bit_cast(unsigned, Wo[(off - OFF_WO) >> 2]);
  } else if (off < OFF_B2) {
    val = __builtin_bit_cast(unsigned, b1[(off - OFF_B1) >> 2]);
  } else if (off < OFF_B3) {
    val = __builtin_bit_cast(unsigned, be1[(off - OFF_B2) >> 2]);
  } else if (off < OFF_B4) {
    int i = (off - OFF_B3) >> 2;
    float v = (i < 6) ? be2[i] : 0.0f;
    val = __builtin_bit_cast(unsigned, v);
  } else if (off < OFF_B5) {
    val = __builtin_bit_cast(unsigned, bd1[(off - OFF_B4) >> 2]);
  } else {
    val = __builtin_bit_cast(unsigned, bd2[(off - OFF_B5) >> 2]);
  }
  *(unsigned*)(g_img + off) = val;
}

// Generic layer: OUT^T = tanh(W^T * IN^T + b). bin = B-frags (2 node subgroups
// x KT k-tiles x 4 packed-f16 regs). pk = packed tanh'd C-frags.
template<int MT, int KT>
static __device__ __forceinline__ void layer_mm(const char* smem, int woff, int boff,
    const int (&bin)[2][KT][4], int (&pk)[2][MT][2], int ln, int q)
{
#pragma unroll
  for (int mi = 0; mi < MT; ++mi) {
    f32x4 bias = *(const f32x4*)(smem + boff + mi * 64 + q * 16);
    f32x4 a0 = bias, a1 = bias;
#pragma unroll
    for (int ki = 0; ki < KT; ++ki) {
      H8 A;
      A.h = *(const half8*)(smem + woff + (mi * KT + ki) * 1024 + ln * 16);
      a0 = MFMA(A, bin[0][ki], a0);
      a1 = MFMA(A, bin[1][ki], a1);
    }
    pk[0][mi][0] = pkrtz(tanh_f(a0[0]), tanh_f(a0[1]));
    pk[0][mi][1] = pkrtz(tanh_f(a0[2]), tanh_f(a0[3]));
    pk[1][mi][0] = pkrtz(tanh_f(a1[0]), tanh_f(a1[1]));
    pk[1][mi][1] = pkrtz(tanh_f(a1[2]), tanh_f(a1[3]));
  }
}

// C-layout (packed pairs) -> next-layer B-operand layout, pure cross-lane.
// Target lane (q,c), frag ki: pulls from frag 2ki+(q>>1), src lanes 32(q&1)+c (+16).
template<int KTN, int MT>
static __device__ __forceinline__ void build_b(const int (&pk)[2][MT][2],
    int (&bo)[2][KTN][4], int s1, int s2, bool qlo)
{
#pragma unroll
  for (int g = 0; g < 2; ++g) {
#pragma unroll
    for (int ki = 0; ki < KTN; ++ki) {
      int lo0 = pk[g][2 * ki][0],     lo1 = pk[g][2 * ki][1];
      int hi0 = pk[g][2 * ki + 1][0], hi1 = pk[g][2 * ki + 1][1];
      int x0 = __shfl(lo0, s1, 64), y0 = __shfl(hi0, s1, 64);
      int x1 = __shfl(lo1, s1, 64), y1 = __shfl(hi1, s1, 64);
      int x2 = __shfl(lo0, s2, 64), y2 = __shfl(hi0, s2, 64);
      int x3 = __shfl(lo1, s2, 64), y3 = __shfl(hi1, s2, 64);
      bo[g][ki][0] = qlo ? x0 : y0;
      bo[g][ki][1] = qlo ? x1 : y1;
      bo[g][ki][2] = qlo ? x2 : y2;
      bo[g][ki][3] = qlo ? x3 : y3;
    }
  }
}

__global__ __launch_bounds__(512, 2) void gnn_main(const float* __restrict__ ea,
                                                   float* __restrict__ out,
                                                   const float* __restrict__ bo_p)
{
  __shared__ __align__(16) char smem[IMG_BYTES];
  const int tid = threadIdx.x;
  const int wv = tid >> 6, ln = tid & 63;

  // ---- stage weight image to LDS once per (persistent) block ----
#pragma unroll 1
  for (int r = 0; r < 19; ++r) {
    int cb = (r * 8 + wv) << 6;   // chunk base for this wave
    __builtin_amdgcn_global_load_lds(
        (const __attribute__((address_space(1))) void*)(g_img + (size_t)(cb + ln) * 16),
        (__attribute__((address_space(3))) void*)(smem + (size_t)cb * 16), 16, 0, 0);
  }
  if (wv == 0 && ln < 4) {
    __builtin_amdgcn_global_load_lds(
        (const __attribute__((address_space(1))) void*)(g_img + (size_t)(9728 + ln) * 16),
        (__attribute__((address_space(3))) void*)(smem + (size_t)9728 * 16), 16, 0, 0);
  }
  __syncthreads();

  const int q = ln >> 4, c = ln & 15;
  const bool qlo = (q < 2);
  const int s1 = ((q & 1) << 5) + c;   // bpermute source lanes
  const int s2 = s1 + 16;
  const float bo = *bo_p;

  const int NT = (N_NODES + 255) / 256;   // 1954 tiles of 256 nodes
#pragma unroll 1
  for (int t = blockIdx.x; t < NT; t += gridDim.x) {
    const int base = t * 256 + wv * 32;   // 32 nodes per wave (2 subgroups of 16)

    // ---- L1 input: edge_attr as X^T (16 feats x nodes), f16 B-frags ----
    int nl = base + (q >> 1) * 16 + c;
    if (nl > N_NODES - 1) nl = N_NODES - 1;
    const f32x4* ea4 = (const f32x4*)ea;
    size_t eb = (size_t)nl * 4 + (size_t)((q & 1) * 2);
    f32x4 vlo = ea4[eb];
    f32x4 vhi = ea4[eb + 1];
    int p0 = pkrtz(vlo[0], vlo[1]), p1 = pkrtz(vlo[2], vlo[3]);
    int p2 = pkrtz(vhi[0], vhi[1]), p3 = pkrtz(vhi[2], vhi[3]);
    int bin1[2][1][4];
    bin1[0][0][0] = qlo ? p0 : 0; bin1[0][0][1] = qlo ? p1 : 0;
    bin1[0][0][2] = qlo ? p2 : 0; bin1[0][0][3] = qlo ? p3 : 0;
    int sh = (ln + 32) & 63;
    int r0 = __shfl(p0, sh, 64), r1 = __shfl(p1, sh, 64);
    int r2 = __shfl(p2, sh, 64), r3 = __shfl(p3, sh, 64);
    bin1[1][0][0] = qlo ? r0 : 0; bin1[1][0][1] = qlo ? r1 : 0;
    bin1[1][0][2] = qlo ? r2 : 0; bin1[1][0][3] = qlo ? r3 : 0;

    // ---- L1: 16 -> 256 ----
    int pk1[2][16][2];
#pragma unroll
    for (int mi = 0; mi < 16; ++mi) {
      f32x4 bias = *(const f32x4*)(smem + OFF_B1 + mi * 64 + q * 16);
      H8 A;
      A.h = *(const half8*)(smem + OFF_W1 + mi * 512 + (ln & 31) * 16);
      if (!qlo) { A.i[0] = 0; A.i[1] = 0; A.i[2] = 0; A.i[3] = 0; }  // K-pad rows
      f32x4 a0 = bias, a1 = bias;
      a0 = MFMA(A, bin1[0][0], a0);
      a1 = MFMA(A, bin1[1][0], a1);
      pk1[0][mi][0] = pkrtz(tanh_f(a0[0]), tanh_f(a0[1]));
      pk1[0][mi][1] = pkrtz(tanh_f(a0[2]), tanh_f(a0[3]));
      pk1[1][mi][0] = pkrtz(tanh_f(a1[0]), tanh_f(a1[1]));
      pk1[1][mi][1] = pkrtz(tanh_f(a1[2]), tanh_f(a1[3]));
    }

    // ---- L2: 256 -> 128 ----
    int bin2[2][8][4];
    build_b<8, 16>(pk1, bin2, s1, s2, qlo);
    int pk2[2][8][2];
    layer_mm<8, 8>(smem, OFF_W2, OFF_B2, bin2, pk2, ln, q);

    // ---- L3: 128 -> 6 (padded 16; rows 6..15 come out exactly 0) ----
    int bin3[2][4][4];
    build_b<4, 8>(pk2, bin3, s1, s2, qlo);
    int pk3[2][1][2];
    layer_mm<1, 4>(smem, OFF_W3, OFF_B3, bin3, pk3, ln, q);

    // ---- L4: 6 -> 128 (K padded to 32; z[6..15]=0 from L3, k>=16 lanes zeroed) ----
    int bin4[2][1][4];
#pragma unroll
    for (int g = 0; g < 2; ++g) {
      int a0s = __shfl(pk3[g][0][0], s1, 64), a1s = __shfl(pk3[g][0][1], s1, 64);
      int a2s = __shfl(pk3[g][0][0], s2, 64), a3s = __shfl(pk3[g][0][1], s2, 64);
      bin4[g][0][0] = qlo ? a0s : 0;
      bin4[g][0][1] = qlo ? a1s : 0;
      bin4[g][0][2] = qlo ? a2s : 0;
      bin4[g][0][3] = qlo ? a3s : 0;
    }
    int pk4[2][8][2];
    layer_mm<8, 1>(smem, OFF_W4, OFF_B4, bin4, pk4, ln, q);

    // ---- L5: 128 -> 256 (no tanh on d) fused with L6: out = sigmoid(tanh(d).Wo + bo) ----
    int bin5[2][4][4];
    build_b<4, 8>(pk4, bin5, s1, s2, qlo);
    float part0 = 0.0f, part1 = 0.0f;
#pragma unroll
    for (int mi = 0; mi < 16; ++mi) {
      f32x4 bias = *(const f32x4*)(smem + OFF_B5 + mi * 64 + q * 16);
      f32x4 a0 = bias, a1 = bias;
#pragma unroll
      for (int ki = 0; ki < 4; ++ki) {
        H8 A;
        A.h = *(const half8*)(smem + OFF_W5 + (mi * 4 + ki) * 1024 + ln * 16);
        a0 = MFMA(A, bin5[0][ki], a0);
        a1 = MFMA(A, bin5[1][ki], a1);
      }
      f32x4 wo = *(const f32x4*)(smem + OFF_WO + mi * 64 + q * 16);
      part0 += tanh_f(a0[0]) * wo[0] + tanh_f(a0[1]) * wo[1]
             + tanh_f(a0[2]) * wo[2] + tanh_f(a0[3]) * wo[3];
      part1 += tanh_f(a1[0]) * wo[0] + tanh_f(a1[1]) * wo[1]
             + tanh_f(a1[2]) * wo[2] + tanh_f(a1[3]) * wo[3];
    }
    // reduce the 4 quad partials (feature slices) per node
    part0 += __shfl_xor(part0, 16, 64); part0 += __shfl_xor(part0, 32, 64);
    part1 += __shfl_xor(part1, 16, 64); part1 += __shfl_xor(part1, 32, 64);
    if (q < 2) {
      int node = base + q * 16 + c;
      if (node < N_NODES) {
        float v = ((q == 0) ? part0 : part1) + bo;
        out[node] = sigmoid_f(v);
      }
    }
  }
}

extern "C" void kernel_launch(void* const* d_in, const int* in_sizes, int n_in,
                              void* d_out, int out_size, void* d_ws, size_t ws_size,
                              hipStream_t stream) {
  (void)in_sizes; (void)n_in; (void)d_ws; (void)ws_size; (void)out_size;
  // dict order: x(0), edge_index(1), edge_attr(2), W1(3), b1(4), We1(5), be1(6),
  //             We2(7), be2(8), Wd1(9), bd1(10), Wd2(11), bd2(12), Wo(13), bo(14)
  const float* ea  = (const float*)d_in[2];
  const float* W1  = (const float*)d_in[3];
  const float* b1  = (const float*)d_in[4];
  const float* We1 = (const float*)d_in[5];
  const float* be1 = (const float*)d_in[6];
  const float* We2 = (const float*)d_in[7];
  const float* be2 = (const float*)d_in[8];
  const float* Wd1 = (const float*)d_in[9];
  const float* bd1 = (const float*)d_in[10];
  const float* Wd2 = (const float*)d_in[11];
  const float* bd2 = (const float*)d_in[12];
  const float* Wo  = (const float*)d_in[13];
  const float* bo  = (const float*)d_in[14];

  gnn_prep<<<dim3((IMG_BYTES / 4 + 255) / 256), dim3(256), 0, stream>>>(
      W1, b1, We1, be1, We2, be2, Wd1, bd1, Wd2, bd2, Wo);
  gnn_main<<<dim3(256), dim3(512), 0, stream>>>(ea, (float*)d_out, bo);
}